// Round 1
// 99.283 us; speedup vs baseline: 1.0391x; 1.0391x over previous
//
#include <hip/hip_runtime.h>

// DifferentiableRGBtoVel: image (4,3,512,512) fp32, cmap (256,3) fp32, v_i (256) fp32
// out velocities (4,512,512) fp32.
//
// v5 (MFMA logits): logit_k = -K2*|c_k - p|^2 (exp2 units, K2 = 1/(0.01*ln2)).
// Computed on the matrix pipe via one mfma_f32_16x16x32_bf16 per 16px x 16k tile,
// using 3-way bf16 splits for ~fp32 accuracy:
//   slots 0-17 : 2K2*(c . p) via cross products {hh,mh,hm,hl,mm,lh} x 3 channels
//   slots 18-20: -K2*|c|^2   (3-way bf16 split, B side, A = 1)
//   slots 21-23: -K2*|p|^2   (3-way bf16 split, A side, B = -1)
//   slots 24-31: zero
// MFMA output IS the complete logit -> exp2 -> accumulate s, sv per lane.
// Per-lane VALU work per k drops from 6 pk-ops + 2 exp to just exp + 2 scalar ops;
// the kernel becomes transcendental-pipe-bound (268M exp2 total).

typedef __attribute__((ext_vector_type(8))) short short8;   // 8 bf16 = 4 VGPRs
typedef __attribute__((ext_vector_type(4))) float f32x4;

#define HWSZ 262144              // 512*512
#define NPIX 1048576             // 4*512*512
#define K2F  144.2695040888963f  // 1/(0.01*ln2)

// round f32 -> bf16 bits (RNE); residual (exact in fp32) returned via *resid
static __device__ __forceinline__ unsigned f2bf(float x, float* resid) {
  unsigned u = __builtin_bit_cast(unsigned, x);
  unsigned r = (u + 0x7fffu + ((u >> 16) & 1u)) >> 16;
  if (resid) *resid = x - __builtin_bit_cast(float, r << 16);
  return r;
}
static __device__ __forceinline__ unsigned bfp(unsigned lo, unsigned hi) {
  return (lo & 0xffffu) | (hi << 16);
}

// ---- prep: build the B-fragment table (16 tiles x 64 lanes x 16B = 16 KiB) ----
// B-frag lane mapping for 16x16x32: col = lane&15 (color), k-chunk = lane>>4.
// Color k's 32 slots live at btab[(k>>4)*64 + g*16 + (k&15)], chunk g = slots 8g..8g+7.
__global__ __launch_bounds__(256) void rgb2vel_prep(
    const float* __restrict__ cmap, float4* __restrict__ btab) {
  int k = threadIdx.x;  // 256 threads, 1 block
  float c0 = cmap[k * 3 + 0], c1 = cmap[k * 3 + 1], c2 = cmap[k * 3 + 2];
  float cc[3] = {c0, c1, c2};
  unsigned H[3], M[3], L[3];
  float r;
#pragma unroll
  for (int ch = 0; ch < 3; ++ch) {          // 3-way split of 2K2*c
    float x = 2.0f * K2F * cc[ch];
    H[ch] = f2bf(x, &r);
    M[ch] = f2bf(r, &r);
    L[ch] = f2bf(r, nullptr);
  }
  float mcc = -(K2F * (c0 * c0 + c1 * c1 + c2 * c2));
  unsigned mh = f2bf(mcc, &r);
  unsigned mm = f2bf(r, &r);
  unsigned ml = f2bf(r, nullptr);
  const unsigned N1 = 0xBF80u;  // -1.0 bf16
  // B slots: [H0 H1 H2 | H0 H1 H2 | M0 M1 M2 | L0 L1 L2 | M0 M1 M2 | H0 H1 H2 |
  //           mh mm ml | -1 -1 -1 | 0 x8]
  unsigned d[16];
  d[0] = bfp(H[0], H[1]); d[1] = bfp(H[2], H[0]); d[2] = bfp(H[1], H[2]);
  d[3] = bfp(M[0], M[1]); d[4] = bfp(M[2], L[0]); d[5] = bfp(L[1], L[2]);
  d[6] = bfp(M[0], M[1]); d[7] = bfp(M[2], H[0]); d[8] = bfp(H[1], H[2]);
  d[9] = bfp(mh, mm);     d[10] = bfp(ml, N1);    d[11] = bfp(N1, N1);
  d[12] = d[13] = d[14] = d[15] = 0u;
  int col = k & 15, tt = k >> 4;
#pragma unroll
  for (int g = 0; g < 4; ++g) {
    float4 v;
    v.x = __builtin_bit_cast(float, d[4 * g + 0]);
    v.y = __builtin_bit_cast(float, d[4 * g + 1]);
    v.z = __builtin_bit_cast(float, d[4 * g + 2]);
    v.w = __builtin_bit_cast(float, d[4 * g + 3]);
    btab[tt * 64 + g * 16 + col] = v;
  }
}

// ---- main: 4 waves/block, 64 px/wave (4 M-tiles of 16), 16 k-tiles unrolled ----
__global__ __launch_bounds__(256, 2) void rgb2vel_main(
    const float* __restrict__ img, const float4* __restrict__ btab,
    const float* __restrict__ vv, float* __restrict__ out) {
  __shared__ __align__(16) unsigned char smem[4 * 8704];  // per-wave 8704B slice
  const int lane = threadIdx.x & 63;
  const int warp = threadIdx.x >> 6;
  unsigned char* wl = smem + warp * 8704;
  const int wpix = blockIdx.x * 256 + warp * 64;
  const int col = lane & 15;
  const int g = lane >> 4;

  // B-frags + v_k: register-resident for the whole kernel (64 + 16 VGPRs)
  short8 bfr[16];
  float vk[16];
#pragma unroll
  for (int t = 0; t < 16; ++t) {
    bfr[t] = __builtin_bit_cast(short8, btab[t * 64 + lane]);
    vk[t] = vv[t * 16 + col];  // color = t*16 + (lane&15) per C-layout
  }

  // Stage this wave's 64 pixels as A-slot vectors into LDS (80B/pixel row).
  {
    int idx = wpix + lane;
    int n = idx >> 18;              // HWSZ = 2^18
    int hw = idx & (HWSZ - 1);
    const float* pb = img + (size_t)n * 3 * HWSZ + hw;
    float p0 = pb[0], p1 = pb[HWSZ], p2 = pb[2 * HWSZ];  // coalesced per wave
    float pc[3] = {p0, p1, p2};
    unsigned ph[3], pm[3], pl[3];
    float r;
#pragma unroll
    for (int ch = 0; ch < 3; ++ch) {  // 3-way split of p
      ph[ch] = f2bf(pc[ch], &r);
      pm[ch] = f2bf(r, &r);
      pl[ch] = f2bf(r, nullptr);
    }
    float q = K2F * (p0 * p0 + p1 * p1 + p2 * p2);
    unsigned qh = f2bf(q, &r);
    unsigned qm = f2bf(r, &r);
    unsigned ql = f2bf(r, nullptr);
    const unsigned ONE = 0x3F80u;
    // A slots: [ph0 ph1 ph2 | pm0 pm1 pm2 | ph0 ph1 ph2 | ph0 ph1 ph2 |
    //           pm0 pm1 pm2 | pl0 pl1 pl2 | 1 1 1 | qh qm ql | 0 x8]
    int4* sb = (int4*)(wl + lane * 80);
    sb[0] = make_int4((int)bfp(ph[0], ph[1]), (int)bfp(ph[2], pm[0]),
                      (int)bfp(pm[1], pm[2]), (int)bfp(ph[0], ph[1]));
    sb[1] = make_int4((int)bfp(ph[2], ph[0]), (int)bfp(ph[1], ph[2]),
                      (int)bfp(pm[0], pm[1]), (int)bfp(pm[2], pl[0]));
    sb[2] = make_int4((int)bfp(pl[1], pl[2]), (int)bfp(ONE, ONE),
                      (int)bfp(ONE, qh),      (int)bfp(qm, ql));
    sb[3] = make_int4(0, 0, 0, 0);
  }
  __syncthreads();

  // A-frags: lane supplies A[row = lane&15][k-chunk = lane>>4] for each M-tile
  short8 afr[4];
#pragma unroll
  for (int m = 0; m < 4; ++m)
    afr[m] = *(const short8*)(wl + (m * 16 + col) * 80 + g * 16);

  float s[16], sv[16];  // indexed [m*4 + reg] -> pixel m*16 + g*4 + reg
#pragma unroll
  for (int i = 0; i < 16; ++i) { s[i] = 0.f; sv[i] = 0.f; }
  const f32x4 z = {0.f, 0.f, 0.f, 0.f};

#pragma unroll
  for (int t = 0; t < 16; ++t) {
#pragma unroll
    for (int m = 0; m < 4; ++m) {
      f32x4 c = __builtin_amdgcn_mfma_f32_16x16x32_bf16(afr[m], bfr[t], z, 0, 0, 0);
#pragma unroll
      for (int rr = 0; rr < 4; ++rr) {
        float w = __builtin_amdgcn_exp2f(c[rr]);   // logit <= 0 by construction
        s[m * 4 + rr] += w;
        sv[m * 4 + rr] = fmaf(w, vk[t], sv[m * 4 + rr]);
      }
    }
  }

  // Transpose-reduce: each pixel's 256 k-partials live across 16 consecutive
  // lanes (one per color column). LDS layout [pixel][17 float2] (pad -> 2-way
  // max on reads), then lane p sums its 16 partial pairs and stores.
#pragma unroll
  for (int m = 0; m < 4; ++m)
#pragma unroll
    for (int rr = 0; rr < 4; ++rr) {
      int p = m * 16 + g * 4 + rr;
      *(float2*)(wl + (p * 17 + col) * 8) = make_float2(s[m * 4 + rr], sv[m * 4 + rr]);
    }
  __syncthreads();
  float st = 0.f, svt = 0.f;
#pragma unroll
  for (int c2 = 0; c2 < 16; ++c2) {
    float2 v = *(const float2*)(wl + (lane * 17 + c2) * 8);
    st += v.x;
    svt += v.y;
  }
  out[wpix + lane] = svt / st;
}

extern "C" void kernel_launch(void* const* d_in, const int* in_sizes, int n_in,
                              void* d_out, int out_size, void* d_ws, size_t ws_size,
                              hipStream_t stream) {
  const float* image = (const float*)d_in[0];  // (4,3,512,512)
  const float* cmap  = (const float*)d_in[1];  // (256,3)
  const float* v_i   = (const float*)d_in[2];  // (256,)
  float* out = (float*)d_out;                  // (4,512,512)

  float4* btab = (float4*)d_ws;                // 16 KiB B-frag table

  rgb2vel_prep<<<1, 256, 0, stream>>>(cmap, btab);
  rgb2vel_main<<<NPIX / 256, 256, 0, stream>>>(image, btab, v_i, out);
}